// Round 2
// baseline (3588.430 us; speedup 1.0000x reference)
//
#include <hip/hip_runtime.h>
#include <math.h>

// ---------------------------------------------------------------------------
// STAttentionRecBlock fp32, sample-chunked (G samples/pass, G from ws_size).
// 8 logical samples: 0..3 = x, 4..7 = x1. Output flat: sample ns at ns*SAMP.
// Per chunk [n0, n0+G):
//   spatial: in-gemm -> qk; scores; for s: apply_s -> z_s, out-gemm acc;
//            ff-gemm -> d_out
//   temporal: same on d_out in place.
// Workspace per chunk: A (qk 384 rows, then h/acc 256 rows) G*3.84M f |
//   Zs G*2.56M f | attT G*0.48M f | spart G*15000 | atts G*1875
//   = G * 27,587,500 bytes. G adaptively in {8,4,2,1}.
// ---------------------------------------------------------------------------

#define PP 10000          // T*V
#define SAMP 2560000      // C*PP
#define BM 128
#define BN 128
#define BKc 8

__device__ __forceinline__ float4 ld4(const float* p) { return *(const float4*)p; }
__device__ __forceinline__ float lrelu(float v) { return v >= 0.f ? v : 0.1f * v; }

// ---------------------------------------------------------------------------
// Tiled conv-as-GEMM over a chunk. blockIdx.z = ln (chunk-local sample).
// A: W[m][k] with row stride Kw (Kw may exceed K for s-sliced weights).
// B: BGLOB ? global sample ns (split x/x1 at 4) : ws buffer at ln*K*PP.
// out: OUTGLOB ? out + ns*M*PP : out + ln*M*PP.
// MODE 0: out = acc + bias
// MODE 1: out = lrelu(res + g*(acc+bias) + beta)            (ff)
// MODE 2: out = acc                                         (out-gemm s=0)
// MODE 3: out += acc                                        (out-gemm s=1)
// MODE 4: out = lrelu(res + g*(out + acc + bias) + beta)    (out-gemm s=2)
// res (MODE 1,4): global, split rg0/rg1 at ns==4. NOT restrict (may alias out).
// ---------------------------------------------------------------------------
template<int MODE, bool PE, bool BGLOB, bool OUTGLOB>
__global__ __launch_bounds__(256)
void gemm_conv(const float* __restrict__ W, int Kw,
               const float* __restrict__ bias,
               const float* __restrict__ g, const float* __restrict__ beta,
               const float* __restrict__ bg0, const float* __restrict__ bg1,
               const float* __restrict__ bw,
               const float* __restrict__ pe,
               const float* rg0, const float* rg1,
               float* out, int n0, int M, int K)
{
    const int ln = blockIdx.z;
    const int ns = n0 + ln;
    const int p0 = blockIdx.x * BN;
    const int m0 = blockIdx.y * BM;
    const int tid = threadIdx.x;
    const int tx = tid & 15, ty = tid >> 4;

    const float* Bp;
    if (BGLOB)
        Bp = (ns < 4) ? bg0 + (size_t)ns * (size_t)K * PP
                      : bg1 + (size_t)(ns - 4) * (size_t)K * PP;
    else
        Bp = bw + (size_t)ln * (size_t)K * PP;

    __shared__ float As[BKc][BM + 4];
    __shared__ float Bs[BKc][BN + 4];

    float acc[8][8];
#pragma unroll
    for (int i = 0; i < 8; i++)
#pragma unroll
        for (int j = 0; j < 8; j++) acc[i][j] = 0.f;

    const int ar = tid >> 1;        // A row in M-tile (0..127)
    const int ak = (tid & 1) * 4;   // A k offset (0 or 4)
    const int bk = tid >> 5;        // B k row (0..7)
    const int bc = (tid & 31) * 4;  // B col (0..124)
    const bool fullN = (p0 + BN <= PP);

    for (int k0 = 0; k0 < K; k0 += BKc) {
        float4 av = ld4(&W[(size_t)(m0 + ar) * Kw + k0 + ak]);
        float bv[4];
        if (fullN) {
            float4 t = ld4(&Bp[(size_t)(k0 + bk) * PP + p0 + bc]);
            bv[0] = t.x; bv[1] = t.y; bv[2] = t.z; bv[3] = t.w;
            if (PE) {
                float4 pv = ld4(&pe[(size_t)(k0 + bk) * PP + p0 + bc]);
                bv[0] += pv.x; bv[1] += pv.y; bv[2] += pv.z; bv[3] += pv.w;
            }
        } else {
#pragma unroll
            for (int e = 0; e < 4; e++) {
                int p = p0 + bc + e;
                float v = 0.f;
                if (p < PP) {
                    v = Bp[(size_t)(k0 + bk) * PP + p];
                    if (PE) v += pe[(size_t)(k0 + bk) * PP + p];
                }
                bv[e] = v;
            }
        }
        __syncthreads();
        As[ak + 0][ar] = av.x;
        As[ak + 1][ar] = av.y;
        As[ak + 2][ar] = av.z;
        As[ak + 3][ar] = av.w;
        *(float4*)&Bs[bk][bc] = make_float4(bv[0], bv[1], bv[2], bv[3]);
        __syncthreads();
#pragma unroll
        for (int kk = 0; kk < BKc; kk++) {
            float4 a0 = ld4(&As[kk][ty * 8]);
            float4 a1 = ld4(&As[kk][ty * 8 + 4]);
            float4 b0 = ld4(&Bs[kk][tx * 4]);
            float4 b1 = ld4(&Bs[kk][64 + tx * 4]);
            float aR[8] = {a0.x, a0.y, a0.z, a0.w, a1.x, a1.y, a1.z, a1.w};
            float bR[8] = {b0.x, b0.y, b0.z, b0.w, b1.x, b1.y, b1.z, b1.w};
#pragma unroll
            for (int i = 0; i < 8; i++)
#pragma unroll
                for (int j = 0; j < 8; j++)
                    acc[i][j] = fmaf(aR[i], bR[j], acc[i][j]);
        }
    }

    float* op = out + (OUTGLOB ? (size_t)ns : (size_t)ln) * (size_t)M * PP;
    const float* resp = nullptr;
    if (MODE == 1 || MODE == 4)
        resp = (ns < 4) ? rg0 + (size_t)ns * SAMP : rg1 + (size_t)(ns - 4) * SAMP;

#pragma unroll
    for (int i = 0; i < 8; i++) {
        int m = m0 + ty * 8 + i;
        float bi = (MODE == 0 || MODE == 1 || MODE == 4) ? bias[m] : 0.f;
        float gi = (MODE == 1 || MODE == 4) ? g[m] : 0.f;
        float be = (MODE == 1 || MODE == 4) ? beta[m] : 0.f;
        size_t rowoff = (size_t)m * PP;
#pragma unroll
        for (int h4 = 0; h4 < 2; h4++) {
            int pb = p0 + h4 * 64 + tx * 4;
#pragma unroll
            for (int jj = 0; jj < 4; jj++) {
                int p = pb + jj;
                if (!fullN && p >= PP) continue;
                float a = acc[i][h4 * 4 + jj];
                float val;
                if (MODE == 0)      val = a + bi;
                else if (MODE == 2) val = a;
                else if (MODE == 3) val = op[rowoff + p] + a;
                else if (MODE == 4) val = lrelu(resp[rowoff + p] + gi * (op[rowoff + p] + a + bi) + be);
                else                val = lrelu(resp[rowoff + p] + gi * (a + bi) + be);
                op[rowoff + p] = val;
            }
        }
    }
}

// ---------------------------------------------------------------------------
// Spatial scores, partial K: dot[u][v] = sum over rows r=(c*400+t) of
// qsec[r*25+u]*ksec[r*25+v].  Grid (chunk=8, s=3, ln=G); 3200 rows per block.
// ---------------------------------------------------------------------------
__global__ __launch_bounds__(256)
void scores_s_partial(const float* __restrict__ qk, float* __restrict__ spart)
{
    const int chunk = blockIdx.x, s = blockIdx.y, ln = blockIdx.z;
    const float* qsec = qk + ((size_t)ln * 384 + s * 64) * PP;
    const float* ksec = qk + ((size_t)ln * 384 + (3 + s) * 64) * PP;
    __shared__ float QL[800];
    __shared__ float KL[800];
    const int tid = threadIdx.x;
    const int o0 = tid, o1 = tid + 256, o2 = tid + 512;
    const int u0 = o0 / 25, v0 = o0 % 25;
    const int u1 = o1 / 25, v1 = o1 % 25;
    const int u2 = o2 / 25, v2 = o2 % 25;
    float a0 = 0.f, a1 = 0.f, a2 = 0.f;
    const size_t base = (size_t)chunk * 80000;
    for (int blk = 0; blk < 100; blk++) {
        __syncthreads();
        for (int i = tid; i < 800; i += 256) {
            QL[i] = qsec[base + blk * 800 + i];
            KL[i] = ksec[base + blk * 800 + i];
        }
        __syncthreads();
#pragma unroll 4
        for (int rr = 0; rr < 32; rr++) {
            int ro = rr * 25;
            a0 = fmaf(QL[ro + u0], KL[ro + v0], a0);
            a1 = fmaf(QL[ro + u1], KL[ro + v1], a1);
            if (tid < 113) a2 = fmaf(QL[ro + u2], KL[ro + v2], a2);
        }
    }
    float* sp = spart + ((size_t)(ln * 3 + s) * 8 + chunk) * 625;
    sp[o0] = a0;
    sp[o1] = a1;
    if (tid < 113) sp[o2] = a2;
}

// grid.x = 3*G blocks (idx = ln*3+s), 640 threads.
__global__ void scores_s_final(const float* __restrict__ spart,
                               const float* __restrict__ alphas,
                               const float* __restrict__ att0s,
                               float* __restrict__ atts)
{
    const int idx = blockIdx.x;
    const int s = idx % 3;
    const int o = threadIdx.x;
    if (o >= 625) return;
    float sum = 0.f;
#pragma unroll
    for (int i = 0; i < 8; i++) sum += spart[((size_t)idx * 8 + i) * 625 + o];
    atts[(size_t)idx * 625 + o] = tanhf(sum * (1.f / 25600.f)) * alphas[s] + att0s[s * 625 + o];
}

// ---------------------------------------------------------------------------
// Spatial apply (one s): z[ln][c][t][w] = sum_v x[ns][c][t][v] * atts[ln][s][v][w]
// Grid (200, G). Thread owns 2 consecutive rows r=(c*400+t).
// ---------------------------------------------------------------------------
__global__ __launch_bounds__(256)
void apply_s_kernel(const float* __restrict__ x0, const float* __restrict__ x1,
                    const float* __restrict__ atts, float* __restrict__ z,
                    int n0, int s)
{
    const int ln = blockIdx.y;
    const int ns = n0 + ln;
    const int tid = threadIdx.x;
    __shared__ float attL[700];   // 25*28 padded
    for (int i = tid; i < 700; i += 256) attL[i] = 0.f;
    __syncthreads();
    for (int i = tid; i < 625; i += 256) {
        int v = i / 25, w = i % 25;
        attL[v * 28 + w] = atts[(size_t)ln * 1875 + s * 625 + i];
    }
    __syncthreads();
    const float* xp = (ns < 4) ? x0 + (size_t)ns * SAMP : x1 + (size_t)(ns - 4) * SAMP;
    const int r0 = (blockIdx.x * 256 + tid) * 2;   // even; both rows share c
    const float* xr0 = xp + (size_t)r0 * 25;
    float xr[2][25];
#pragma unroll
    for (int i = 0; i < 2; i++)
#pragma unroll
        for (int v = 0; v < 25; v++) xr[i][v] = xr0[i * 25 + v];
    const int c0 = r0 / 400, t0 = r0 % 400;

    float4 acc0[7], acc1[7];
#pragma unroll
    for (int w4 = 0; w4 < 7; w4++) {
        acc0[w4] = make_float4(0.f, 0.f, 0.f, 0.f);
        acc1[w4] = make_float4(0.f, 0.f, 0.f, 0.f);
    }
#pragma unroll
    for (int v = 0; v < 25; v++) {
        const float4* arow = (const float4*)&attL[v * 28];
        float xv0 = xr[0][v], xv1 = xr[1][v];
#pragma unroll
        for (int w4 = 0; w4 < 7; w4++) {
            float4 a = arow[w4];
            acc0[w4].x = fmaf(xv0, a.x, acc0[w4].x);
            acc0[w4].y = fmaf(xv0, a.y, acc0[w4].y);
            acc0[w4].z = fmaf(xv0, a.z, acc0[w4].z);
            acc0[w4].w = fmaf(xv0, a.w, acc0[w4].w);
            acc1[w4].x = fmaf(xv1, a.x, acc1[w4].x);
            acc1[w4].y = fmaf(xv1, a.y, acc1[w4].y);
            acc1[w4].z = fmaf(xv1, a.z, acc1[w4].z);
            acc1[w4].w = fmaf(xv1, a.w, acc1[w4].w);
        }
    }
    float* zp = z + (size_t)ln * SAMP + (size_t)c0 * PP + (size_t)t0 * 25;
#pragma unroll
    for (int w4 = 0; w4 < 7; w4++) {
        int wb = w4 * 4;
        if (wb + 0 < 25) zp[wb + 0] = acc0[w4].x;
        if (wb + 1 < 25) zp[wb + 1] = acc0[w4].y;
        if (wb + 2 < 25) zp[wb + 2] = acc0[w4].z;
        if (wb + 3 < 25) zp[wb + 3] = acc0[w4].w;
    }
#pragma unroll
    for (int w4 = 0; w4 < 7; w4++) {
        int wb = w4 * 4;
        if (wb + 0 < 25) zp[25 + wb + 0] = acc1[w4].x;
        if (wb + 1 < 25) zp[25 + wb + 1] = acc1[w4].y;
        if (wb + 2 < 25) zp[25 + wb + 2] = acc1[w4].z;
        if (wb + 3 < 25) zp[25 + wb + 3] = acc1[w4].w;
    }
}

// ---------------------------------------------------------------------------
// Temporal scores: attT[(ln*3+s)][q][t] = tanh(sum_{c,v} q[c,t,v]k[c,q,v]/1600)
//                                          * alphat[s] + att0t[s][t][q]
// Grid (7, 7, 3*G); 64x64 (q,t) tile; K looped over c.
// ---------------------------------------------------------------------------
__global__ __launch_bounds__(256)
void scores_t_kernel(const float* __restrict__ qk, const float* __restrict__ alphat,
                     const float* __restrict__ att0t, float* __restrict__ attT)
{
    const int idx = blockIdx.z, s = idx % 3;
    const int ln = idx / 3;
    const int q0 = blockIdx.y * 64, t0 = blockIdx.x * 64;
    const float* qsec = qk + ((size_t)ln * 384 + s * 64) * PP;
    const float* ksec = qk + ((size_t)ln * 384 + (3 + s) * 64) * PP;
    __shared__ float QT[25][68];   // [v][t-local]
    __shared__ float KT[25][68];   // [v][q-local]
    const int tid = threadIdx.x, tx = tid & 15, ty = tid >> 4;
    float acc[4][4];
#pragma unroll
    for (int i = 0; i < 4; i++)
#pragma unroll
        for (int j = 0; j < 4; j++) acc[i][j] = 0.f;
    const int row0 = tid / 25, vv0 = tid % 25;

    for (int c = 0; c < 64; c++) {
        __syncthreads();
        int row = row0, v = vv0;
        for (int i = tid; i < 1600; i += 256) {
            int t = t0 + row;
            QT[v][row] = (t < 400) ? qsec[(size_t)c * PP + t * 25 + v] : 0.f;
            int q = q0 + row;
            KT[v][row] = (q < 400) ? ksec[(size_t)c * PP + q * 25 + v] : 0.f;
            v += 6; row += 10;
            if (v >= 25) { v -= 25; row += 1; }
        }
        __syncthreads();
#pragma unroll
        for (int v2 = 0; v2 < 25; v2++) {
            float4 kv = ld4(&KT[v2][ty * 4]);
            float4 qv = ld4(&QT[v2][tx * 4]);
            float kR[4] = {kv.x, kv.y, kv.z, kv.w};
            float qR[4] = {qv.x, qv.y, qv.z, qv.w};
#pragma unroll
            for (int i = 0; i < 4; i++)
#pragma unroll
                for (int j = 0; j < 4; j++)
                    acc[i][j] = fmaf(kR[i], qR[j], acc[i][j]);
        }
    }
    const float alpha = alphat[s];
    float* attTp = attT + (size_t)idx * 160000;
#pragma unroll
    for (int i = 0; i < 4; i++) {
        int q = q0 + ty * 4 + i;
        if (q >= 400) continue;
#pragma unroll
        for (int j = 0; j < 4; j++) {
            int t = t0 + tx * 4 + j;
            if (t >= 400) continue;
            attTp[(size_t)q * 400 + t] = tanhf(acc[i][j] * (1.f / 1600.f)) * alpha
                                       + att0t[((size_t)s * 400 + t) * 400 + q];
        }
    }
}

// ---------------------------------------------------------------------------
// Temporal apply (one s): z[ln][c][q][v] = sum_t attT[(ln*3+s)][q][t]*y[ns][c][t][v]
// Grid (50, 4, G): M=q (400), N=j=(c*25+v) (6400), K=t (400).
// ---------------------------------------------------------------------------
__global__ __launch_bounds__(256)
void apply_t_kernel(const float* __restrict__ y, const float* __restrict__ attT,
                    float* __restrict__ z, int n0, int s)
{
    const int ln = blockIdx.z;
    const int ns = n0 + ln;
    const int j0 = blockIdx.x * 128;
    const int q0 = blockIdx.y * 128;
    const float* A = attT + ((size_t)ln * 3 + s) * 160000;
    const float* Y = y + (size_t)ns * SAMP;
    float* zout = z + (size_t)ln * SAMP;
    __shared__ float As[BKc][BM + 4];
    __shared__ float Bs[BKc][BN + 4];
    const int tid = threadIdx.x, tx = tid & 15, ty = tid >> 4;
    const int ar = tid >> 1, ak = (tid & 1) * 4;
    const int bk = tid >> 5;
    const int bj = (tid & 31) * 4;
    int bcc[4], bvv[4];
#pragma unroll
    for (int e = 0; e < 4; e++) { int j = j0 + bj + e; bcc[e] = j / 25; bvv[e] = j % 25; }
    float acc[8][8];
#pragma unroll
    for (int i = 0; i < 8; i++)
#pragma unroll
        for (int j = 0; j < 8; j++) acc[i][j] = 0.f;
    const int qA = q0 + ar;

    for (int k0 = 0; k0 < 400; k0 += BKc) {
        float4 av = make_float4(0.f, 0.f, 0.f, 0.f);
        if (qA < 400) av = ld4(&A[(size_t)qA * 400 + k0 + ak]);
        float bload[4];
#pragma unroll
        for (int e = 0; e < 4; e++)
            bload[e] = Y[(size_t)bcc[e] * PP + (size_t)(k0 + bk) * 25 + bvv[e]];
        __syncthreads();
        As[ak + 0][ar] = av.x;
        As[ak + 1][ar] = av.y;
        As[ak + 2][ar] = av.z;
        As[ak + 3][ar] = av.w;
        *(float4*)&Bs[bk][bj] = make_float4(bload[0], bload[1], bload[2], bload[3]);
        __syncthreads();
#pragma unroll
        for (int kk = 0; kk < BKc; kk++) {
            float4 a0 = ld4(&As[kk][ty * 8]);
            float4 a1 = ld4(&As[kk][ty * 8 + 4]);
            float4 b0 = ld4(&Bs[kk][tx * 4]);
            float4 b1 = ld4(&Bs[kk][64 + tx * 4]);
            float aR[8] = {a0.x, a0.y, a0.z, a0.w, a1.x, a1.y, a1.z, a1.w};
            float bR[8] = {b0.x, b0.y, b0.z, b0.w, b1.x, b1.y, b1.z, b1.w};
#pragma unroll
            for (int i = 0; i < 8; i++)
#pragma unroll
                for (int j = 0; j < 8; j++)
                    acc[i][j] = fmaf(aR[i], bR[j], acc[i][j]);
        }
    }

    int cS[8], vS[8];
#pragma unroll
    for (int jj = 0; jj < 4; jj++) {
        int j = j0 + tx * 4 + jj;       cS[jj] = j / 25;      vS[jj] = j % 25;
        int j2 = j0 + 64 + tx * 4 + jj; cS[4 + jj] = j2 / 25; vS[4 + jj] = j2 % 25;
    }
#pragma unroll
    for (int i = 0; i < 8; i++) {
        int q = q0 + ty * 8 + i;
        if (q >= 400) continue;
#pragma unroll
        for (int jj = 0; jj < 8; jj++)
            zout[(size_t)cS[jj] * PP + (size_t)q * 25 + vS[jj]] = acc[i][jj];
    }
}

// ---------------------------------------------------------------------------
extern "C" void kernel_launch(void* const* d_in, const int* in_sizes, int n_in,
                              void* d_out, int out_size, void* d_ws, size_t ws_size,
                              hipStream_t stream)
{
    const float* x    = (const float*)d_in[0];
    const float* x1   = (const float*)d_in[1];
    const float* pe_s = (const float*)d_in[2];
    const float* pe_t = (const float*)d_in[3];
    const float* Wsi  = (const float*)d_in[4];
    const float* bsi  = (const float*)d_in[5];
    const float* alphas = (const float*)d_in[6];
    const float* att0s  = (const float*)d_in[7];
    const float* Wso  = (const float*)d_in[8];
    const float* bso  = (const float*)d_in[9];
    const float* gso  = (const float*)d_in[10];
    const float* beso = (const float*)d_in[11];
    const float* Wsf  = (const float*)d_in[12];
    const float* bsf  = (const float*)d_in[13];
    const float* gsf  = (const float*)d_in[14];
    const float* besf = (const float*)d_in[15];
    const float* Wti  = (const float*)d_in[16];
    const float* bti  = (const float*)d_in[17];
    const float* alphat = (const float*)d_in[18];
    const float* att0t  = (const float*)d_in[19];
    const float* Wto  = (const float*)d_in[20];
    const float* bto  = (const float*)d_in[21];
    const float* gto  = (const float*)d_in[22];
    const float* beto = (const float*)d_in[23];
    const float* Wtf  = (const float*)d_in[24];
    const float* btf  = (const float*)d_in[25];
    const float* gtf  = (const float*)d_in[26];
    const float* betf = (const float*)d_in[27];

    float* outp = (float*)d_out;
    const float* outpB = outp + 4ull * SAMP;   // samples 4..7 view

    int G = 1;
    for (int g = 8; g >= 1; g >>= 1) {
        if ((size_t)g * 27587500ull <= ws_size) { G = g; break; }
    }

    float* A   = (float*)d_ws;                       // qk then h/acc
    float* Zs  = A  + (size_t)G * 3840000ull;        // z one-s slice
    float* aT  = Zs + (size_t)G * 2560000ull;        // temporal att
    float* sp  = aT + (size_t)G * 480000ull;         // spatial score partials
    float* as  = sp + (size_t)G * 15000ull;          // spatial att

    dim3 blk(256);
    for (int n0 = 0; n0 < 8; n0 += G) {
        dim3 gIn(79, 3, G), gOut(79, 2, G);

        // ---- spatial stage (input x / x1) ----
        gemm_conv<0, true, true, false><<<gIn, blk, 0, stream>>>(
            Wsi, 256, bsi, nullptr, nullptr, x, x1, nullptr, pe_s,
            nullptr, nullptr, A, n0, 384, 256);
        scores_s_partial<<<dim3(8, 3, G), blk, 0, stream>>>(A, sp);
        scores_s_final<<<dim3(3 * G), dim3(640), 0, stream>>>(sp, alphas, att0s, as);
        for (int s = 0; s < 3; s++) {
            apply_s_kernel<<<dim3(200, G), blk, 0, stream>>>(x, x1, as, Zs, n0, s);
            if (s == 0)
                gemm_conv<2, false, false, false><<<gOut, blk, 0, stream>>>(
                    Wso + s * 256, 768, nullptr, nullptr, nullptr, nullptr, nullptr, Zs,
                    nullptr, nullptr, nullptr, A, n0, 256, 256);
            else if (s == 1)
                gemm_conv<3, false, false, false><<<gOut, blk, 0, stream>>>(
                    Wso + s * 256, 768, nullptr, nullptr, nullptr, nullptr, nullptr, Zs,
                    nullptr, nullptr, nullptr, A, n0, 256, 256);
            else
                gemm_conv<4, false, false, false><<<gOut, blk, 0, stream>>>(
                    Wso + s * 256, 768, bso, gso, beso, nullptr, nullptr, Zs,
                    nullptr, x, x1, A, n0, 256, 256);
        }
        gemm_conv<1, false, false, true><<<gOut, blk, 0, stream>>>(
            Wsf, 256, bsf, gsf, besf, nullptr, nullptr, A, nullptr,
            x, x1, outp, n0, 256, 256);

        // ---- temporal stage (input d_out, in place) ----
        gemm_conv<0, true, true, false><<<gIn, blk, 0, stream>>>(
            Wti, 256, bti, nullptr, nullptr, outp, outpB, nullptr, pe_t,
            nullptr, nullptr, A, n0, 384, 256);
        scores_t_kernel<<<dim3(7, 7, 3 * G), blk, 0, stream>>>(A, alphat, att0t, aT);
        for (int s = 0; s < 3; s++) {
            apply_t_kernel<<<dim3(50, 4, G), blk, 0, stream>>>(outp, aT, Zs, n0, s);
            if (s == 0)
                gemm_conv<2, false, false, false><<<gOut, blk, 0, stream>>>(
                    Wto + s * 256, 768, nullptr, nullptr, nullptr, nullptr, nullptr, Zs,
                    nullptr, nullptr, nullptr, A, n0, 256, 256);
            else if (s == 1)
                gemm_conv<3, false, false, false><<<gOut, blk, 0, stream>>>(
                    Wto + s * 256, 768, nullptr, nullptr, nullptr, nullptr, nullptr, Zs,
                    nullptr, nullptr, nullptr, A, n0, 256, 256);
            else
                gemm_conv<4, false, false, false><<<gOut, blk, 0, stream>>>(
                    Wto + s * 256, 768, bto, gto, beto, nullptr, nullptr, Zs,
                    nullptr, outp, outpB, A, n0, 256, 256);
        }
        gemm_conv<1, false, false, true><<<gOut, blk, 0, stream>>>(
            Wtf, 256, btf, gtf, betf, nullptr, nullptr, A, nullptr,
            outp, outpB, outp, n0, 256, 256);
    }
}

// Round 3
// 3404.898 us; speedup vs baseline: 1.0539x; 1.0539x over previous
//
#include <hip/hip_runtime.h>
#include <math.h>

// ---------------------------------------------------------------------------
// STAttentionRecBlock fp32, sample-chunked (G samples/pass, G from ws_size).
// 8 logical samples: 0..3 = x, 4..7 = x1. Output flat: sample ns at ns*SAMP.
// R3: temporal in-GEMM writes transposed qkT[sec][t][v*64+cl] (MODE 5);
//     scores_t is now a tiled NT-GEMM (K-split 2, partials in Zs) + finalize.
// Workspace per chunk-sample: A 3.84M f (qk/qkT, then h overlay) | Zs 2.56M f
//   (z-slice / scores_t partials) | aT 0.48M f | sp 15000 | as 1875
//   = 27,587,500 B per G. G adaptive in {8,4,2,1}.
// ---------------------------------------------------------------------------

#define PP 10000          // T*V
#define SAMP 2560000      // C*PP
#define BM 128
#define BN 128
#define BKc 8

__device__ __forceinline__ float4 ld4(const float* p) { return *(const float4*)p; }
__device__ __forceinline__ float lrelu(float v) { return v >= 0.f ? v : 0.1f * v; }

// ---------------------------------------------------------------------------
// Tiled conv-as-GEMM over a chunk. blockIdx.z = ln (chunk-local sample).
// MODE 0: out = acc + bias
// MODE 1: out = lrelu(res + g*(acc+bias) + beta)            (ff)
// MODE 2: out = acc                                         (out-gemm s=0)
// MODE 3: out += acc                                        (out-gemm s=1)
// MODE 4: out = lrelu(res + g*(out + acc + bias) + beta)    (out-gemm s=2)
// MODE 5: out = acc + bias, written as qkT[sec][t][v*64+cl] (temporal in-gemm)
// ---------------------------------------------------------------------------
template<int MODE, bool PE, bool BGLOB, bool OUTGLOB>
__global__ __launch_bounds__(256)
void gemm_conv(const float* __restrict__ W, int Kw,
               const float* __restrict__ bias,
               const float* __restrict__ g, const float* __restrict__ beta,
               const float* __restrict__ bg0, const float* __restrict__ bg1,
               const float* __restrict__ bw,
               const float* __restrict__ pe,
               const float* rg0, const float* rg1,
               float* out, int n0, int M, int K)
{
    const int ln = blockIdx.z;
    const int ns = n0 + ln;
    const int p0 = blockIdx.x * BN;
    const int m0 = blockIdx.y * BM;
    const int tid = threadIdx.x;
    const int tx = tid & 15, ty = tid >> 4;

    const float* Bp;
    if (BGLOB)
        Bp = (ns < 4) ? bg0 + (size_t)ns * (size_t)K * PP
                      : bg1 + (size_t)(ns - 4) * (size_t)K * PP;
    else
        Bp = bw + (size_t)ln * (size_t)K * PP;

    __shared__ float As[BKc][BM + 4];
    __shared__ float Bs[BKc][BN + 4];

    float acc[8][8];
#pragma unroll
    for (int i = 0; i < 8; i++)
#pragma unroll
        for (int j = 0; j < 8; j++) acc[i][j] = 0.f;

    const int ar = tid >> 1;        // A row in M-tile (0..127)
    const int ak = (tid & 1) * 4;   // A k offset (0 or 4)
    const int bk = tid >> 5;        // B k row (0..7)
    const int bc = (tid & 31) * 4;  // B col (0..124)
    const bool fullN = (p0 + BN <= PP);

    for (int k0 = 0; k0 < K; k0 += BKc) {
        float4 av = ld4(&W[(size_t)(m0 + ar) * Kw + k0 + ak]);
        float bv[4];
        if (fullN) {
            float4 t = ld4(&Bp[(size_t)(k0 + bk) * PP + p0 + bc]);
            bv[0] = t.x; bv[1] = t.y; bv[2] = t.z; bv[3] = t.w;
            if (PE) {
                float4 pv = ld4(&pe[(size_t)(k0 + bk) * PP + p0 + bc]);
                bv[0] += pv.x; bv[1] += pv.y; bv[2] += pv.z; bv[3] += pv.w;
            }
        } else {
#pragma unroll
            for (int e = 0; e < 4; e++) {
                int p = p0 + bc + e;
                float v = 0.f;
                if (p < PP) {
                    v = Bp[(size_t)(k0 + bk) * PP + p];
                    if (PE) v += pe[(size_t)(k0 + bk) * PP + p];
                }
                bv[e] = v;
            }
        }
        __syncthreads();
        As[ak + 0][ar] = av.x;
        As[ak + 1][ar] = av.y;
        As[ak + 2][ar] = av.z;
        As[ak + 3][ar] = av.w;
        *(float4*)&Bs[bk][bc] = make_float4(bv[0], bv[1], bv[2], bv[3]);
        __syncthreads();
#pragma unroll
        for (int kk = 0; kk < BKc; kk++) {
            float4 a0 = ld4(&As[kk][ty * 8]);
            float4 a1 = ld4(&As[kk][ty * 8 + 4]);
            float4 b0 = ld4(&Bs[kk][tx * 4]);
            float4 b1 = ld4(&Bs[kk][64 + tx * 4]);
            float aR[8] = {a0.x, a0.y, a0.z, a0.w, a1.x, a1.y, a1.z, a1.w};
            float bR[8] = {b0.x, b0.y, b0.z, b0.w, b1.x, b1.y, b1.z, b1.w};
#pragma unroll
            for (int i = 0; i < 8; i++)
#pragma unroll
                for (int j = 0; j < 8; j++)
                    acc[i][j] = fmaf(aR[i], bR[j], acc[i][j]);
        }
    }

    if (MODE == 5) {
        // Transposed write: qkT[ln][sec][t][v*64 + cl], sec=m/64, cl=m%64.
        // Thread's 8 m-rows are consecutive within one 64-block -> 2 float4s.
        const int mrow = m0 + ty * 8;
        const int sec = mrow >> 6;
        const int cl0 = mrow & 63;
        float* qt = out + (size_t)ln * 3840000ull + (size_t)sec * 640000ull + cl0;
        float bi[8];
#pragma unroll
        for (int i = 0; i < 8; i++) bi[i] = bias[mrow + i];
#pragma unroll
        for (int h4 = 0; h4 < 2; h4++) {
#pragma unroll
            for (int jj = 0; jj < 4; jj++) {
                int p = p0 + h4 * 64 + tx * 4 + jj;
                if (p >= PP) continue;
                int t = p / 25, v = p - t * 25;
                float* dst = qt + (size_t)t * 1600 + v * 64;
                int cj = h4 * 4 + jj;
                *(float4*)dst = make_float4(acc[0][cj] + bi[0], acc[1][cj] + bi[1],
                                            acc[2][cj] + bi[2], acc[3][cj] + bi[3]);
                *(float4*)(dst + 4) = make_float4(acc[4][cj] + bi[4], acc[5][cj] + bi[5],
                                                  acc[6][cj] + bi[6], acc[7][cj] + bi[7]);
            }
        }
        return;
    }

    float* op = out + (OUTGLOB ? (size_t)ns : (size_t)ln) * (size_t)M * PP;
    const float* resp = nullptr;
    if (MODE == 1 || MODE == 4)
        resp = (ns < 4) ? rg0 + (size_t)ns * SAMP : rg1 + (size_t)(ns - 4) * SAMP;

#pragma unroll
    for (int i = 0; i < 8; i++) {
        int m = m0 + ty * 8 + i;
        float bi = (MODE == 0 || MODE == 1 || MODE == 4) ? bias[m] : 0.f;
        float gi = (MODE == 1 || MODE == 4) ? g[m] : 0.f;
        float be = (MODE == 1 || MODE == 4) ? beta[m] : 0.f;
        size_t rowoff = (size_t)m * PP;
#pragma unroll
        for (int h4 = 0; h4 < 2; h4++) {
            int pb = p0 + h4 * 64 + tx * 4;
#pragma unroll
            for (int jj = 0; jj < 4; jj++) {
                int p = pb + jj;
                if (!fullN && p >= PP) continue;
                float a = acc[i][h4 * 4 + jj];
                float val;
                if (MODE == 0)      val = a + bi;
                else if (MODE == 2) val = a;
                else if (MODE == 3) val = op[rowoff + p] + a;
                else if (MODE == 4) val = lrelu(resp[rowoff + p] + gi * (op[rowoff + p] + a + bi) + be);
                else                val = lrelu(resp[rowoff + p] + gi * (a + bi) + be);
                op[rowoff + p] = val;
            }
        }
    }
}

// ---------------------------------------------------------------------------
// Spatial scores, partial K: dot[u][v] = sum over rows r=(c*400+t) of
// qsec[r*25+u]*ksec[r*25+v].  Grid (chunk=8, s=3, ln=G); 3200 rows per block.
// ---------------------------------------------------------------------------
__global__ __launch_bounds__(256)
void scores_s_partial(const float* __restrict__ qk, float* __restrict__ spart)
{
    const int chunk = blockIdx.x, s = blockIdx.y, ln = blockIdx.z;
    const float* qsec = qk + ((size_t)ln * 384 + s * 64) * PP;
    const float* ksec = qk + ((size_t)ln * 384 + (3 + s) * 64) * PP;
    __shared__ float QL[800];
    __shared__ float KL[800];
    const int tid = threadIdx.x;
    const int o0 = tid, o1 = tid + 256, o2 = tid + 512;
    const int u0 = o0 / 25, v0 = o0 % 25;
    const int u1 = o1 / 25, v1 = o1 % 25;
    const int u2 = o2 / 25, v2 = o2 % 25;
    float a0 = 0.f, a1 = 0.f, a2 = 0.f;
    const size_t base = (size_t)chunk * 80000;
    for (int blk = 0; blk < 100; blk++) {
        __syncthreads();
        for (int i = tid; i < 800; i += 256) {
            QL[i] = qsec[base + blk * 800 + i];
            KL[i] = ksec[base + blk * 800 + i];
        }
        __syncthreads();
#pragma unroll 4
        for (int rr = 0; rr < 32; rr++) {
            int ro = rr * 25;
            a0 = fmaf(QL[ro + u0], KL[ro + v0], a0);
            a1 = fmaf(QL[ro + u1], KL[ro + v1], a1);
            if (tid < 113) a2 = fmaf(QL[ro + u2], KL[ro + v2], a2);
        }
    }
    float* sp = spart + ((size_t)(ln * 3 + s) * 8 + chunk) * 625;
    sp[o0] = a0;
    sp[o1] = a1;
    if (tid < 113) sp[o2] = a2;
}

// grid.x = 3*G blocks (idx = ln*3+s), 640 threads.
__global__ void scores_s_final(const float* __restrict__ spart,
                               const float* __restrict__ alphas,
                               const float* __restrict__ att0s,
                               float* __restrict__ atts)
{
    const int idx = blockIdx.x;
    const int s = idx % 3;
    const int o = threadIdx.x;
    if (o >= 625) return;
    float sum = 0.f;
#pragma unroll
    for (int i = 0; i < 8; i++) sum += spart[((size_t)idx * 8 + i) * 625 + o];
    atts[(size_t)idx * 625 + o] = tanhf(sum * (1.f / 25600.f)) * alphas[s] + att0s[s * 625 + o];
}

// ---------------------------------------------------------------------------
// Spatial apply (one s): z[ln][c][t][w] = sum_v x[ns][c][t][v] * atts[ln][s][v][w]
// Grid (200, G). Thread owns 2 consecutive rows r=(c*400+t).
// ---------------------------------------------------------------------------
__global__ __launch_bounds__(256)
void apply_s_kernel(const float* __restrict__ x0, const float* __restrict__ x1,
                    const float* __restrict__ atts, float* __restrict__ z,
                    int n0, int s)
{
    const int ln = blockIdx.y;
    const int ns = n0 + ln;
    const int tid = threadIdx.x;
    __shared__ float attL[700];   // 25*28 padded
    for (int i = tid; i < 700; i += 256) attL[i] = 0.f;
    __syncthreads();
    for (int i = tid; i < 625; i += 256) {
        int v = i / 25, w = i % 25;
        attL[v * 28 + w] = atts[(size_t)ln * 1875 + s * 625 + i];
    }
    __syncthreads();
    const float* xp = (ns < 4) ? x0 + (size_t)ns * SAMP : x1 + (size_t)(ns - 4) * SAMP;
    const int r0 = (blockIdx.x * 256 + tid) * 2;   // even; both rows share c
    const float* xr0 = xp + (size_t)r0 * 25;
    float xr[2][25];
#pragma unroll
    for (int i = 0; i < 2; i++)
#pragma unroll
        for (int v = 0; v < 25; v++) xr[i][v] = xr0[i * 25 + v];
    const int c0 = r0 / 400, t0 = r0 % 400;

    float4 acc0[7], acc1[7];
#pragma unroll
    for (int w4 = 0; w4 < 7; w4++) {
        acc0[w4] = make_float4(0.f, 0.f, 0.f, 0.f);
        acc1[w4] = make_float4(0.f, 0.f, 0.f, 0.f);
    }
#pragma unroll
    for (int v = 0; v < 25; v++) {
        const float4* arow = (const float4*)&attL[v * 28];
        float xv0 = xr[0][v], xv1 = xr[1][v];
#pragma unroll
        for (int w4 = 0; w4 < 7; w4++) {
            float4 a = arow[w4];
            acc0[w4].x = fmaf(xv0, a.x, acc0[w4].x);
            acc0[w4].y = fmaf(xv0, a.y, acc0[w4].y);
            acc0[w4].z = fmaf(xv0, a.z, acc0[w4].z);
            acc0[w4].w = fmaf(xv0, a.w, acc0[w4].w);
            acc1[w4].x = fmaf(xv1, a.x, acc1[w4].x);
            acc1[w4].y = fmaf(xv1, a.y, acc1[w4].y);
            acc1[w4].z = fmaf(xv1, a.z, acc1[w4].z);
            acc1[w4].w = fmaf(xv1, a.w, acc1[w4].w);
        }
    }
    float* zp = z + (size_t)ln * SAMP + (size_t)c0 * PP + (size_t)t0 * 25;
#pragma unroll
    for (int w4 = 0; w4 < 7; w4++) {
        int wb = w4 * 4;
        if (wb + 0 < 25) zp[wb + 0] = acc0[w4].x;
        if (wb + 1 < 25) zp[wb + 1] = acc0[w4].y;
        if (wb + 2 < 25) zp[wb + 2] = acc0[w4].z;
        if (wb + 3 < 25) zp[wb + 3] = acc0[w4].w;
    }
#pragma unroll
    for (int w4 = 0; w4 < 7; w4++) {
        int wb = w4 * 4;
        if (wb + 0 < 25) zp[25 + wb + 0] = acc1[w4].x;
        if (wb + 1 < 25) zp[25 + wb + 1] = acc1[w4].y;
        if (wb + 2 < 25) zp[25 + wb + 2] = acc1[w4].z;
        if (wb + 3 < 25) zp[25 + wb + 3] = acc1[w4].w;
    }
}

// ---------------------------------------------------------------------------
// Temporal scores GEMM: part[(idx*2+ks)][q][t] = sum_{k in half ks}
//   qkT[ln][3+s][q][k] * qkT[ln][s][t][k].   64x64 tile, 4x4/thread, K=800.
// Grid (49, 2, 3*G).
// ---------------------------------------------------------------------------
__global__ __launch_bounds__(256)
void scores_t_gemm(const float* __restrict__ qkT, float* __restrict__ part)
{
    const int idx = blockIdx.z;
    const int s = idx % 3, ln = idx / 3;
    const int ks = blockIdx.y;
    const int q0 = (blockIdx.x / 7) * 64, t0 = (blockIdx.x % 7) * 64;
    const float* base = qkT + (size_t)ln * 3840000ull;
    const float* Aq = base + (size_t)(3 + s) * 640000ull;   // rows = q
    const float* Bt = base + (size_t)s * 640000ull;         // rows = t
    __shared__ float As[8][68];
    __shared__ float Bs[8][68];
    const int tid = threadIdx.x, tx = tid & 15, ty = tid >> 4;
    float acc[4][4];
#pragma unroll
    for (int i = 0; i < 4; i++)
#pragma unroll
        for (int j = 0; j < 4; j++) acc[i][j] = 0.f;

    const int half = tid >> 7;          // 0 -> stage A, 1 -> stage B
    const int r = (tid & 127) >> 1;     // 0..63 tile row
    const int ak = (tid & 1) * 4;       // k offset 0/4
    const int row = (half ? t0 : q0) + r;
    const bool rok = row < 400;
    const float* srow = (half ? Bt : Aq) + (size_t)row * 1600 + ks * 800 + ak;
    float* dL = (half ? &Bs[0][0] : &As[0][0]) + ak * 68 + r;

    for (int k0 = 0; k0 < 800; k0 += 8) {
        float4 v = make_float4(0.f, 0.f, 0.f, 0.f);
        if (rok) v = ld4(srow + k0);
        __syncthreads();
        dL[0] = v.x; dL[68] = v.y; dL[136] = v.z; dL[204] = v.w;
        __syncthreads();
#pragma unroll
        for (int kk = 0; kk < 8; kk++) {
            float4 a = ld4(&As[kk][ty * 4]);
            float4 b = ld4(&Bs[kk][tx * 4]);
            float aR[4] = {a.x, a.y, a.z, a.w};
            float bR[4] = {b.x, b.y, b.z, b.w};
#pragma unroll
            for (int i = 0; i < 4; i++)
#pragma unroll
                for (int j = 0; j < 4; j++)
                    acc[i][j] = fmaf(aR[i], bR[j], acc[i][j]);
        }
    }

    float* pp_ = part + ((size_t)idx * 2 + ks) * 160000ull;
#pragma unroll
    for (int i = 0; i < 4; i++) {
        int q = q0 + ty * 4 + i;
        if (q >= 400) continue;
        int t = t0 + tx * 4;
        if (t + 3 < 400) {
            *(float4*)&pp_[(size_t)q * 400 + t] =
                make_float4(acc[i][0], acc[i][1], acc[i][2], acc[i][3]);
        } else {
#pragma unroll
            for (int j = 0; j < 4; j++)
                if (t + j < 400) pp_[(size_t)q * 400 + t + j] = acc[i][j];
        }
    }
}

// part0+part1 -> tanh -> aT[idx][q][t].  Grid (625, 3*G), 256 threads.
__global__ void scores_t_final(const float* __restrict__ part,
                               const float* __restrict__ alphat,
                               const float* __restrict__ att0t,
                               float* __restrict__ aT)
{
    const int idx = blockIdx.y;
    const int s = idx % 3;
    const int o = blockIdx.x * 256 + threadIdx.x;   // q*400+t
    const int q = o / 400, t = o - q * 400;
    float sum = part[(size_t)(idx * 2) * 160000ull + o]
              + part[(size_t)(idx * 2 + 1) * 160000ull + o];
    aT[(size_t)idx * 160000ull + o] =
        tanhf(sum * (1.f / 1600.f)) * alphat[s] + att0t[((size_t)s * 400 + t) * 400 + q];
}

// ---------------------------------------------------------------------------
// Temporal apply (one s): z[ln][c][q][v] = sum_t attT[(ln*3+s)][q][t]*y[ns][c][t][v]
// Grid (50, 4, G): M=q (400), N=j=(c*25+v) (6400), K=t (400).
// ---------------------------------------------------------------------------
__global__ __launch_bounds__(256)
void apply_t_kernel(const float* __restrict__ y, const float* __restrict__ attT,
                    float* __restrict__ z, int n0, int s)
{
    const int ln = blockIdx.z;
    const int ns = n0 + ln;
    const int j0 = blockIdx.x * 128;
    const int q0 = blockIdx.y * 128;
    const float* A = attT + ((size_t)ln * 3 + s) * 160000;
    const float* Y = y + (size_t)ns * SAMP;
    float* zout = z + (size_t)ln * SAMP;
    __shared__ float As[BKc][BM + 4];
    __shared__ float Bs[BKc][BN + 4];
    const int tid = threadIdx.x, tx = tid & 15, ty = tid >> 4;
    const int ar = tid >> 1, ak = (tid & 1) * 4;
    const int bk = tid >> 5;
    const int bj = (tid & 31) * 4;
    int bcc[4], bvv[4];
#pragma unroll
    for (int e = 0; e < 4; e++) { int j = j0 + bj + e; bcc[e] = j / 25; bvv[e] = j % 25; }
    float acc[8][8];
#pragma unroll
    for (int i = 0; i < 8; i++)
#pragma unroll
        for (int j = 0; j < 8; j++) acc[i][j] = 0.f;
    const int qA = q0 + ar;

    for (int k0 = 0; k0 < 400; k0 += BKc) {
        float4 av = make_float4(0.f, 0.f, 0.f, 0.f);
        if (qA < 400) av = ld4(&A[(size_t)qA * 400 + k0 + ak]);
        float bload[4];
#pragma unroll
        for (int e = 0; e < 4; e++)
            bload[e] = Y[(size_t)bcc[e] * PP + (size_t)(k0 + bk) * 25 + bvv[e]];
        __syncthreads();
        As[ak + 0][ar] = av.x;
        As[ak + 1][ar] = av.y;
        As[ak + 2][ar] = av.z;
        As[ak + 3][ar] = av.w;
        *(float4*)&Bs[bk][bj] = make_float4(bload[0], bload[1], bload[2], bload[3]);
        __syncthreads();
#pragma unroll
        for (int kk = 0; kk < BKc; kk++) {
            float4 a0 = ld4(&As[kk][ty * 8]);
            float4 a1 = ld4(&As[kk][ty * 8 + 4]);
            float4 b0 = ld4(&Bs[kk][tx * 4]);
            float4 b1 = ld4(&Bs[kk][64 + tx * 4]);
            float aR[8] = {a0.x, a0.y, a0.z, a0.w, a1.x, a1.y, a1.z, a1.w};
            float bR[8] = {b0.x, b0.y, b0.z, b0.w, b1.x, b1.y, b1.z, b1.w};
#pragma unroll
            for (int i = 0; i < 8; i++)
#pragma unroll
                for (int j = 0; j < 8; j++)
                    acc[i][j] = fmaf(aR[i], bR[j], acc[i][j]);
        }
    }

    int cS[8], vS[8];
#pragma unroll
    for (int jj = 0; jj < 4; jj++) {
        int j = j0 + tx * 4 + jj;       cS[jj] = j / 25;      vS[jj] = j % 25;
        int j2 = j0 + 64 + tx * 4 + jj; cS[4 + jj] = j2 / 25; vS[4 + jj] = j2 % 25;
    }
#pragma unroll
    for (int i = 0; i < 8; i++) {
        int q = q0 + ty * 8 + i;
        if (q >= 400) continue;
#pragma unroll
        for (int jj = 0; jj < 8; jj++)
            zout[(size_t)cS[jj] * PP + (size_t)q * 25 + vS[jj]] = acc[i][jj];
    }
}

// ---------------------------------------------------------------------------
extern "C" void kernel_launch(void* const* d_in, const int* in_sizes, int n_in,
                              void* d_out, int out_size, void* d_ws, size_t ws_size,
                              hipStream_t stream)
{
    const float* x    = (const float*)d_in[0];
    const float* x1   = (const float*)d_in[1];
    const float* pe_s = (const float*)d_in[2];
    const float* pe_t = (const float*)d_in[3];
    const float* Wsi  = (const float*)d_in[4];
    const float* bsi  = (const float*)d_in[5];
    const float* alphas = (const float*)d_in[6];
    const float* att0s  = (const float*)d_in[7];
    const float* Wso  = (const float*)d_in[8];
    const float* bso  = (const float*)d_in[9];
    const float* gso  = (const float*)d_in[10];
    const float* beso = (const float*)d_in[11];
    const float* Wsf  = (const float*)d_in[12];
    const float* bsf  = (const float*)d_in[13];
    const float* gsf  = (const float*)d_in[14];
    const float* besf = (const float*)d_in[15];
    const float* Wti  = (const float*)d_in[16];
    const float* bti  = (const float*)d_in[17];
    const float* alphat = (const float*)d_in[18];
    const float* att0t  = (const float*)d_in[19];
    const float* Wto  = (const float*)d_in[20];
    const float* bto  = (const float*)d_in[21];
    const float* gto  = (const float*)d_in[22];
    const float* beto = (const float*)d_in[23];
    const float* Wtf  = (const float*)d_in[24];
    const float* btf  = (const float*)d_in[25];
    const float* gtf  = (const float*)d_in[26];
    const float* betf = (const float*)d_in[27];

    float* outp = (float*)d_out;
    const float* outpB = outp + 4ull * SAMP;   // samples 4..7 view

    int G = 1;
    for (int g = 8; g >= 1; g >>= 1) {
        if ((size_t)g * 27587500ull <= ws_size) { G = g; break; }
    }

    float* A   = (float*)d_ws;                       // qk / qkT, then h overlay
    float* Zs  = A  + (size_t)G * 3840000ull;        // z one-s slice / scores_t partials
    float* aT  = Zs + (size_t)G * 2560000ull;        // temporal att
    float* sp  = aT + (size_t)G * 480000ull;         // spatial score partials
    float* as  = sp + (size_t)G * 15000ull;          // spatial att

    dim3 blk(256);
    for (int n0 = 0; n0 < 8; n0 += G) {
        dim3 gIn(79, 3, G), gOut(79, 2, G);

        // ---- spatial stage (input x / x1) ----
        gemm_conv<0, true, true, false><<<gIn, blk, 0, stream>>>(
            Wsi, 256, bsi, nullptr, nullptr, x, x1, nullptr, pe_s,
            nullptr, nullptr, A, n0, 384, 256);
        scores_s_partial<<<dim3(8, 3, G), blk, 0, stream>>>(A, sp);
        scores_s_final<<<dim3(3 * G), dim3(640), 0, stream>>>(sp, alphas, att0s, as);
        for (int s = 0; s < 3; s++) {
            apply_s_kernel<<<dim3(200, G), blk, 0, stream>>>(x, x1, as, Zs, n0, s);
            if (s == 0)
                gemm_conv<2, false, false, false><<<gOut, blk, 0, stream>>>(
                    Wso + s * 256, 768, nullptr, nullptr, nullptr, nullptr, nullptr, Zs,
                    nullptr, nullptr, nullptr, A, n0, 256, 256);
            else if (s == 1)
                gemm_conv<3, false, false, false><<<gOut, blk, 0, stream>>>(
                    Wso + s * 256, 768, nullptr, nullptr, nullptr, nullptr, nullptr, Zs,
                    nullptr, nullptr, nullptr, A, n0, 256, 256);
            else
                gemm_conv<4, false, false, false><<<gOut, blk, 0, stream>>>(
                    Wso + s * 256, 768, bso, gso, beso, nullptr, nullptr, Zs,
                    nullptr, x, x1, A, n0, 256, 256);
        }
        gemm_conv<1, false, false, true><<<gOut, blk, 0, stream>>>(
            Wsf, 256, bsf, gsf, besf, nullptr, nullptr, A, nullptr,
            x, x1, outp, n0, 256, 256);

        // ---- temporal stage (input d_out, in place) ----
        gemm_conv<5, true, true, false><<<gIn, blk, 0, stream>>>(
            Wti, 256, bti, nullptr, nullptr, outp, outpB, nullptr, pe_t,
            nullptr, nullptr, A, n0, 384, 256);
        scores_t_gemm<<<dim3(49, 2, 3 * G), blk, 0, stream>>>(A, Zs);
        scores_t_final<<<dim3(625, 3 * G), blk, 0, stream>>>(Zs, alphat, att0t, aT);
        for (int s = 0; s < 3; s++) {
            apply_t_kernel<<<dim3(50, 4, G), blk, 0, stream>>>(outp, aT, Zs, n0, s);
            if (s == 0)
                gemm_conv<2, false, false, false><<<gOut, blk, 0, stream>>>(
                    Wto + s * 256, 768, nullptr, nullptr, nullptr, nullptr, nullptr, Zs,
                    nullptr, nullptr, nullptr, A, n0, 256, 256);
            else if (s == 1)
                gemm_conv<3, false, false, false><<<gOut, blk, 0, stream>>>(
                    Wto + s * 256, 768, nullptr, nullptr, nullptr, nullptr, nullptr, Zs,
                    nullptr, nullptr, nullptr, A, n0, 256, 256);
            else
                gemm_conv<4, false, false, false><<<gOut, blk, 0, stream>>>(
                    Wto + s * 256, 768, bto, gto, beto, nullptr, nullptr, Zs,
                    nullptr, outp, outpB, A, n0, 256, 256);
        }
        gemm_conv<1, false, false, true><<<gOut, blk, 0, stream>>>(
            Wtf, 256, btf, gtf, betf, nullptr, nullptr, A, nullptr,
            outp, outpB, outp, n0, 256, 256);
    }
}

// Round 4
// 3175.043 us; speedup vs baseline: 1.1302x; 1.0724x over previous
//
#include <hip/hip_runtime.h>
#include <math.h>

// ---------------------------------------------------------------------------
// STAttentionRecBlock fp32, sample-chunked (G samples/pass, G from ws_size).
// 8 logical samples: 0..3 = x, 4..7 = x1. Output flat: sample ns at ns*SAMP.
// R3: temporal in-GEMM writes transposed qkT (MODE 5); scores_t = tiled GEMM.
// R4: scores_s re-chunked 8->200 blocks/(s,ln) (was 48-block latency-bound,
//     300us/dispatch @ VALUBusy 4.9%); partials now live in Zs.
// Workspace per chunk-sample: A 3.84M f | Zs 2.56M f | aT 0.48M f | sp 15000
//   | as 1875 = 27,587,500 B per G. G adaptive in {8,4,2,1}.
// ---------------------------------------------------------------------------

#define PP 10000          // T*V
#define SAMP 2560000      // C*PP
#define BM 128
#define BN 128
#define BKc 8

__device__ __forceinline__ float4 ld4(const float* p) { return *(const float4*)p; }
__device__ __forceinline__ float lrelu(float v) { return v >= 0.f ? v : 0.1f * v; }

// ---------------------------------------------------------------------------
// Tiled conv-as-GEMM over a chunk. blockIdx.z = ln (chunk-local sample).
// MODE 0: out = acc + bias
// MODE 1: out = lrelu(res + g*(acc+bias) + beta)            (ff)
// MODE 2: out = acc                                         (out-gemm s=0)
// MODE 3: out += acc                                        (out-gemm s=1)
// MODE 4: out = lrelu(res + g*(out + acc + bias) + beta)    (out-gemm s=2)
// MODE 5: out = acc + bias, written as qkT[sec][t][v*64+cl] (temporal in-gemm)
// ---------------------------------------------------------------------------
template<int MODE, bool PE, bool BGLOB, bool OUTGLOB>
__global__ __launch_bounds__(256)
void gemm_conv(const float* __restrict__ W, int Kw,
               const float* __restrict__ bias,
               const float* __restrict__ g, const float* __restrict__ beta,
               const float* __restrict__ bg0, const float* __restrict__ bg1,
               const float* __restrict__ bw,
               const float* __restrict__ pe,
               const float* rg0, const float* rg1,
               float* out, int n0, int M, int K)
{
    const int ln = blockIdx.z;
    const int ns = n0 + ln;
    const int p0 = blockIdx.x * BN;
    const int m0 = blockIdx.y * BM;
    const int tid = threadIdx.x;
    const int tx = tid & 15, ty = tid >> 4;

    const float* Bp;
    if (BGLOB)
        Bp = (ns < 4) ? bg0 + (size_t)ns * (size_t)K * PP
                      : bg1 + (size_t)(ns - 4) * (size_t)K * PP;
    else
        Bp = bw + (size_t)ln * (size_t)K * PP;

    __shared__ float As[BKc][BM + 4];
    __shared__ float Bs[BKc][BN + 4];

    float acc[8][8];
#pragma unroll
    for (int i = 0; i < 8; i++)
#pragma unroll
        for (int j = 0; j < 8; j++) acc[i][j] = 0.f;

    const int ar = tid >> 1;        // A row in M-tile (0..127)
    const int ak = (tid & 1) * 4;   // A k offset (0 or 4)
    const int bk = tid >> 5;        // B k row (0..7)
    const int bc = (tid & 31) * 4;  // B col (0..124)
    const bool fullN = (p0 + BN <= PP);

    for (int k0 = 0; k0 < K; k0 += BKc) {
        float4 av = ld4(&W[(size_t)(m0 + ar) * Kw + k0 + ak]);
        float bv[4];
        if (fullN) {
            float4 t = ld4(&Bp[(size_t)(k0 + bk) * PP + p0 + bc]);
            bv[0] = t.x; bv[1] = t.y; bv[2] = t.z; bv[3] = t.w;
            if (PE) {
                float4 pv = ld4(&pe[(size_t)(k0 + bk) * PP + p0 + bc]);
                bv[0] += pv.x; bv[1] += pv.y; bv[2] += pv.z; bv[3] += pv.w;
            }
        } else {
#pragma unroll
            for (int e = 0; e < 4; e++) {
                int p = p0 + bc + e;
                float v = 0.f;
                if (p < PP) {
                    v = Bp[(size_t)(k0 + bk) * PP + p];
                    if (PE) v += pe[(size_t)(k0 + bk) * PP + p];
                }
                bv[e] = v;
            }
        }
        __syncthreads();
        As[ak + 0][ar] = av.x;
        As[ak + 1][ar] = av.y;
        As[ak + 2][ar] = av.z;
        As[ak + 3][ar] = av.w;
        *(float4*)&Bs[bk][bc] = make_float4(bv[0], bv[1], bv[2], bv[3]);
        __syncthreads();
#pragma unroll
        for (int kk = 0; kk < BKc; kk++) {
            float4 a0 = ld4(&As[kk][ty * 8]);
            float4 a1 = ld4(&As[kk][ty * 8 + 4]);
            float4 b0 = ld4(&Bs[kk][tx * 4]);
            float4 b1 = ld4(&Bs[kk][64 + tx * 4]);
            float aR[8] = {a0.x, a0.y, a0.z, a0.w, a1.x, a1.y, a1.z, a1.w};
            float bR[8] = {b0.x, b0.y, b0.z, b0.w, b1.x, b1.y, b1.z, b1.w};
#pragma unroll
            for (int i = 0; i < 8; i++)
#pragma unroll
                for (int j = 0; j < 8; j++)
                    acc[i][j] = fmaf(aR[i], bR[j], acc[i][j]);
        }
    }

    if (MODE == 5) {
        // Transposed write: qkT[ln][sec][t][v*64 + cl], sec=m/64, cl=m%64.
        const int mrow = m0 + ty * 8;
        const int sec = mrow >> 6;
        const int cl0 = mrow & 63;
        float* qt = out + (size_t)ln * 3840000ull + (size_t)sec * 640000ull + cl0;
        float bi[8];
#pragma unroll
        for (int i = 0; i < 8; i++) bi[i] = bias[mrow + i];
#pragma unroll
        for (int h4 = 0; h4 < 2; h4++) {
#pragma unroll
            for (int jj = 0; jj < 4; jj++) {
                int p = p0 + h4 * 64 + tx * 4 + jj;
                if (p >= PP) continue;
                int t = p / 25, v = p - t * 25;
                float* dst = qt + (size_t)t * 1600 + v * 64;
                int cj = h4 * 4 + jj;
                *(float4*)dst = make_float4(acc[0][cj] + bi[0], acc[1][cj] + bi[1],
                                            acc[2][cj] + bi[2], acc[3][cj] + bi[3]);
                *(float4*)(dst + 4) = make_float4(acc[4][cj] + bi[4], acc[5][cj] + bi[5],
                                                  acc[6][cj] + bi[6], acc[7][cj] + bi[7]);
            }
        }
        return;
    }

    float* op = out + (OUTGLOB ? (size_t)ns : (size_t)ln) * (size_t)M * PP;
    const float* resp = nullptr;
    if (MODE == 1 || MODE == 4)
        resp = (ns < 4) ? rg0 + (size_t)ns * SAMP : rg1 + (size_t)(ns - 4) * SAMP;

#pragma unroll
    for (int i = 0; i < 8; i++) {
        int m = m0 + ty * 8 + i;
        float bi = (MODE == 0 || MODE == 1 || MODE == 4) ? bias[m] : 0.f;
        float gi = (MODE == 1 || MODE == 4) ? g[m] : 0.f;
        float be = (MODE == 1 || MODE == 4) ? beta[m] : 0.f;
        size_t rowoff = (size_t)m * PP;
#pragma unroll
        for (int h4 = 0; h4 < 2; h4++) {
            int pb = p0 + h4 * 64 + tx * 4;
#pragma unroll
            for (int jj = 0; jj < 4; jj++) {
                int p = pb + jj;
                if (!fullN && p >= PP) continue;
                float a = acc[i][h4 * 4 + jj];
                float val;
                if (MODE == 0)      val = a + bi;
                else if (MODE == 2) val = a;
                else if (MODE == 3) val = op[rowoff + p] + a;
                else if (MODE == 4) val = lrelu(resp[rowoff + p] + gi * (op[rowoff + p] + a + bi) + be);
                else                val = lrelu(resp[rowoff + p] + gi * (a + bi) + be);
                op[rowoff + p] = val;
            }
        }
    }
}

// ---------------------------------------------------------------------------
// Spatial scores, partial K (R4): 200 chunks of 128 rows. Grid (200, 3, G).
// dot[u][v] partial = sum_{r in chunk} qsec[r*25+u]*ksec[r*25+v].
// Each block stages its 2x3200 contiguous floats once, one barrier.
// ---------------------------------------------------------------------------
__global__ __launch_bounds__(256)
void scores_s_partial(const float* __restrict__ qk, float* __restrict__ part)
{
    const int chunk = blockIdx.x, s = blockIdx.y, ln = blockIdx.z;
    const float* qsec = qk + ((size_t)ln * 384 + s * 64) * PP + (size_t)chunk * 3200;
    const float* ksec = qk + ((size_t)ln * 384 + (3 + s) * 64) * PP + (size_t)chunk * 3200;
    __shared__ float QL[3200];
    __shared__ float KL[3200];
    const int tid = threadIdx.x;
    for (int i = tid; i < 3200; i += 256) {
        QL[i] = qsec[i];
        KL[i] = ksec[i];
    }
    __syncthreads();
    const int o0 = tid, o1 = tid + 256, o2 = tid + 512;
    const int u0 = o0 / 25, v0 = o0 % 25;
    const int u1 = o1 / 25, v1 = o1 % 25;
    const int u2 = o2 / 25, v2 = o2 % 25;
    float a0 = 0.f, a1 = 0.f, a2 = 0.f;
#pragma unroll 8
    for (int r = 0; r < 128; r++) {
        int ro = r * 25;
        a0 = fmaf(QL[ro + u0], KL[ro + v0], a0);
        a1 = fmaf(QL[ro + u1], KL[ro + v1], a1);
        if (tid < 113) a2 = fmaf(QL[ro + u2], KL[ro + v2], a2);
    }
    float* pp = part + (((size_t)(ln * 3 + s)) * 200 + chunk) * 625;
    pp[o0] = a0;
    pp[o1] = a1;
    if (tid < 113) pp[o2] = a2;
}

// grid.x = 3*G blocks (idx = ln*3+s), 640 threads. Sums 200 partials.
__global__ void scores_s_final(const float* __restrict__ part,
                               const float* __restrict__ alphas,
                               const float* __restrict__ att0s,
                               float* __restrict__ atts)
{
    const int idx = blockIdx.x;
    const int s = idx % 3;
    const int o = threadIdx.x;
    if (o >= 625) return;
    const float* pb = part + (size_t)idx * 200 * 625 + o;
    float sum = 0.f;
#pragma unroll 8
    for (int i = 0; i < 200; i++) sum += pb[(size_t)i * 625];
    atts[(size_t)idx * 625 + o] = tanhf(sum * (1.f / 25600.f)) * alphas[s] + att0s[s * 625 + o];
}

// ---------------------------------------------------------------------------
// Spatial apply (one s): z[ln][c][t][w] = sum_v x[ns][c][t][v] * atts[ln][s][v][w]
// Grid (200, G). Thread owns 2 consecutive rows r=(c*400+t).
// ---------------------------------------------------------------------------
__global__ __launch_bounds__(256)
void apply_s_kernel(const float* __restrict__ x0, const float* __restrict__ x1,
                    const float* __restrict__ atts, float* __restrict__ z,
                    int n0, int s)
{
    const int ln = blockIdx.y;
    const int ns = n0 + ln;
    const int tid = threadIdx.x;
    __shared__ float attL[700];   // 25*28 padded
    for (int i = tid; i < 700; i += 256) attL[i] = 0.f;
    __syncthreads();
    for (int i = tid; i < 625; i += 256) {
        int v = i / 25, w = i % 25;
        attL[v * 28 + w] = atts[(size_t)ln * 1875 + s * 625 + i];
    }
    __syncthreads();
    const float* xp = (ns < 4) ? x0 + (size_t)ns * SAMP : x1 + (size_t)(ns - 4) * SAMP;
    const int r0 = (blockIdx.x * 256 + tid) * 2;   // even; both rows share c
    const float* xr0 = xp + (size_t)r0 * 25;
    float xr[2][25];
#pragma unroll
    for (int i = 0; i < 2; i++)
#pragma unroll
        for (int v = 0; v < 25; v++) xr[i][v] = xr0[i * 25 + v];
    const int c0 = r0 / 400, t0 = r0 % 400;

    float4 acc0[7], acc1[7];
#pragma unroll
    for (int w4 = 0; w4 < 7; w4++) {
        acc0[w4] = make_float4(0.f, 0.f, 0.f, 0.f);
        acc1[w4] = make_float4(0.f, 0.f, 0.f, 0.f);
    }
#pragma unroll
    for (int v = 0; v < 25; v++) {
        const float4* arow = (const float4*)&attL[v * 28];
        float xv0 = xr[0][v], xv1 = xr[1][v];
#pragma unroll
        for (int w4 = 0; w4 < 7; w4++) {
            float4 a = arow[w4];
            acc0[w4].x = fmaf(xv0, a.x, acc0[w4].x);
            acc0[w4].y = fmaf(xv0, a.y, acc0[w4].y);
            acc0[w4].z = fmaf(xv0, a.z, acc0[w4].z);
            acc0[w4].w = fmaf(xv0, a.w, acc0[w4].w);
            acc1[w4].x = fmaf(xv1, a.x, acc1[w4].x);
            acc1[w4].y = fmaf(xv1, a.y, acc1[w4].y);
            acc1[w4].z = fmaf(xv1, a.z, acc1[w4].z);
            acc1[w4].w = fmaf(xv1, a.w, acc1[w4].w);
        }
    }
    float* zp = z + (size_t)ln * SAMP + (size_t)c0 * PP + (size_t)t0 * 25;
#pragma unroll
    for (int w4 = 0; w4 < 7; w4++) {
        int wb = w4 * 4;
        if (wb + 0 < 25) zp[wb + 0] = acc0[w4].x;
        if (wb + 1 < 25) zp[wb + 1] = acc0[w4].y;
        if (wb + 2 < 25) zp[wb + 2] = acc0[w4].z;
        if (wb + 3 < 25) zp[wb + 3] = acc0[w4].w;
    }
#pragma unroll
    for (int w4 = 0; w4 < 7; w4++) {
        int wb = w4 * 4;
        if (wb + 0 < 25) zp[25 + wb + 0] = acc1[w4].x;
        if (wb + 1 < 25) zp[25 + wb + 1] = acc1[w4].y;
        if (wb + 2 < 25) zp[25 + wb + 2] = acc1[w4].z;
        if (wb + 3 < 25) zp[25 + wb + 3] = acc1[w4].w;
    }
}

// ---------------------------------------------------------------------------
// Temporal scores GEMM: part[(idx*2+ks)][q][t] = sum_{k in half ks}
//   qkT[ln][3+s][q][k] * qkT[ln][s][t][k].   64x64 tile, 4x4/thread, K=800.
// Grid (49, 2, 3*G).
// ---------------------------------------------------------------------------
__global__ __launch_bounds__(256)
void scores_t_gemm(const float* __restrict__ qkT, float* __restrict__ part)
{
    const int idx = blockIdx.z;
    const int s = idx % 3, ln = idx / 3;
    const int ks = blockIdx.y;
    const int q0 = (blockIdx.x / 7) * 64, t0 = (blockIdx.x % 7) * 64;
    const float* base = qkT + (size_t)ln * 3840000ull;
    const float* Aq = base + (size_t)(3 + s) * 640000ull;   // rows = q
    const float* Bt = base + (size_t)s * 640000ull;         // rows = t
    __shared__ float As[8][68];
    __shared__ float Bs[8][68];
    const int tid = threadIdx.x, tx = tid & 15, ty = tid >> 4;
    float acc[4][4];
#pragma unroll
    for (int i = 0; i < 4; i++)
#pragma unroll
        for (int j = 0; j < 4; j++) acc[i][j] = 0.f;

    const int half = tid >> 7;          // 0 -> stage A, 1 -> stage B
    const int r = (tid & 127) >> 1;     // 0..63 tile row
    const int ak = (tid & 1) * 4;       // k offset 0/4
    const int row = (half ? t0 : q0) + r;
    const bool rok = row < 400;
    const float* srow = (half ? Bt : Aq) + (size_t)row * 1600 + ks * 800 + ak;
    float* dL = (half ? &Bs[0][0] : &As[0][0]) + ak * 68 + r;

    for (int k0 = 0; k0 < 800; k0 += 8) {
        float4 v = make_float4(0.f, 0.f, 0.f, 0.f);
        if (rok) v = ld4(srow + k0);
        __syncthreads();
        dL[0] = v.x; dL[68] = v.y; dL[136] = v.z; dL[204] = v.w;
        __syncthreads();
#pragma unroll
        for (int kk = 0; kk < 8; kk++) {
            float4 a = ld4(&As[kk][ty * 4]);
            float4 b = ld4(&Bs[kk][tx * 4]);
            float aR[4] = {a.x, a.y, a.z, a.w};
            float bR[4] = {b.x, b.y, b.z, b.w};
#pragma unroll
            for (int i = 0; i < 4; i++)
#pragma unroll
                for (int j = 0; j < 4; j++)
                    acc[i][j] = fmaf(aR[i], bR[j], acc[i][j]);
        }
    }

    float* pp_ = part + ((size_t)idx * 2 + ks) * 160000ull;
#pragma unroll
    for (int i = 0; i < 4; i++) {
        int q = q0 + ty * 4 + i;
        if (q >= 400) continue;
        int t = t0 + tx * 4;
        if (t + 3 < 400) {
            *(float4*)&pp_[(size_t)q * 400 + t] =
                make_float4(acc[i][0], acc[i][1], acc[i][2], acc[i][3]);
        } else {
#pragma unroll
            for (int j = 0; j < 4; j++)
                if (t + j < 400) pp_[(size_t)q * 400 + t + j] = acc[i][j];
        }
    }
}

// part0+part1 -> tanh -> aT[idx][q][t].  Grid (625, 3*G), 256 threads.
__global__ void scores_t_final(const float* __restrict__ part,
                               const float* __restrict__ alphat,
                               const float* __restrict__ att0t,
                               float* __restrict__ aT)
{
    const int idx = blockIdx.y;
    const int s = idx % 3;
    const int o = blockIdx.x * 256 + threadIdx.x;   // q*400+t
    const int q = o / 400, t = o - q * 400;
    float sum = part[(size_t)(idx * 2) * 160000ull + o]
              + part[(size_t)(idx * 2 + 1) * 160000ull + o];
    aT[(size_t)idx * 160000ull + o] =
        tanhf(sum * (1.f / 1600.f)) * alphat[s] + att0t[((size_t)s * 400 + t) * 400 + q];
}

// ---------------------------------------------------------------------------
// Temporal apply (one s): z[ln][c][q][v] = sum_t attT[(ln*3+s)][q][t]*y[ns][c][t][v]
// Grid (50, 4, G): M=q (400), N=j=(c*25+v) (6400), K=t (400).
// ---------------------------------------------------------------------------
__global__ __launch_bounds__(256)
void apply_t_kernel(const float* __restrict__ y, const float* __restrict__ attT,
                    float* __restrict__ z, int n0, int s)
{
    const int ln = blockIdx.z;
    const int ns = n0 + ln;
    const int j0 = blockIdx.x * 128;
    const int q0 = blockIdx.y * 128;
    const float* A = attT + ((size_t)ln * 3 + s) * 160000;
    const float* Y = y + (size_t)ns * SAMP;
    float* zout = z + (size_t)ln * SAMP;
    __shared__ float As[BKc][BM + 4];
    __shared__ float Bs[BKc][BN + 4];
    const int tid = threadIdx.x, tx = tid & 15, ty = tid >> 4;
    const int ar = tid >> 1, ak = (tid & 1) * 4;
    const int bk = tid >> 5;
    const int bj = (tid & 31) * 4;
    int bcc[4], bvv[4];
#pragma unroll
    for (int e = 0; e < 4; e++) { int j = j0 + bj + e; bcc[e] = j / 25; bvv[e] = j % 25; }
    float acc[8][8];
#pragma unroll
    for (int i = 0; i < 8; i++)
#pragma unroll
        for (int j = 0; j < 8; j++) acc[i][j] = 0.f;
    const int qA = q0 + ar;

    for (int k0 = 0; k0 < 400; k0 += BKc) {
        float4 av = make_float4(0.f, 0.f, 0.f, 0.f);
        if (qA < 400) av = ld4(&A[(size_t)qA * 400 + k0 + ak]);
        float bload[4];
#pragma unroll
        for (int e = 0; e < 4; e++)
            bload[e] = Y[(size_t)bcc[e] * PP + (size_t)(k0 + bk) * 25 + bvv[e]];
        __syncthreads();
        As[ak + 0][ar] = av.x;
        As[ak + 1][ar] = av.y;
        As[ak + 2][ar] = av.z;
        As[ak + 3][ar] = av.w;
        *(float4*)&Bs[bk][bj] = make_float4(bload[0], bload[1], bload[2], bload[3]);
        __syncthreads();
#pragma unroll
        for (int kk = 0; kk < BKc; kk++) {
            float4 a0 = ld4(&As[kk][ty * 8]);
            float4 a1 = ld4(&As[kk][ty * 8 + 4]);
            float4 b0 = ld4(&Bs[kk][tx * 4]);
            float4 b1 = ld4(&Bs[kk][64 + tx * 4]);
            float aR[8] = {a0.x, a0.y, a0.z, a0.w, a1.x, a1.y, a1.z, a1.w};
            float bR[8] = {b0.x, b0.y, b0.z, b0.w, b1.x, b1.y, b1.z, b1.w};
#pragma unroll
            for (int i = 0; i < 8; i++)
#pragma unroll
                for (int j = 0; j < 8; j++)
                    acc[i][j] = fmaf(aR[i], bR[j], acc[i][j]);
        }
    }

    int cS[8], vS[8];
#pragma unroll
    for (int jj = 0; jj < 4; jj++) {
        int j = j0 + tx * 4 + jj;       cS[jj] = j / 25;      vS[jj] = j % 25;
        int j2 = j0 + 64 + tx * 4 + jj; cS[4 + jj] = j2 / 25; vS[4 + jj] = j2 % 25;
    }
#pragma unroll
    for (int i = 0; i < 8; i++) {
        int q = q0 + ty * 8 + i;
        if (q >= 400) continue;
#pragma unroll
        for (int jj = 0; jj < 8; jj++)
            zout[(size_t)cS[jj] * PP + (size_t)q * 25 + vS[jj]] = acc[i][jj];
    }
}

// ---------------------------------------------------------------------------
extern "C" void kernel_launch(void* const* d_in, const int* in_sizes, int n_in,
                              void* d_out, int out_size, void* d_ws, size_t ws_size,
                              hipStream_t stream)
{
    const float* x    = (const float*)d_in[0];
    const float* x1   = (const float*)d_in[1];
    const float* pe_s = (const float*)d_in[2];
    const float* pe_t = (const float*)d_in[3];
    const float* Wsi  = (const float*)d_in[4];
    const float* bsi  = (const float*)d_in[5];
    const float* alphas = (const float*)d_in[6];
    const float* att0s  = (const float*)d_in[7];
    const float* Wso  = (const float*)d_in[8];
    const float* bso  = (const float*)d_in[9];
    const float* gso  = (const float*)d_in[10];
    const float* beso = (const float*)d_in[11];
    const float* Wsf  = (const float*)d_in[12];
    const float* bsf  = (const float*)d_in[13];
    const float* gsf  = (const float*)d_in[14];
    const float* besf = (const float*)d_in[15];
    const float* Wti  = (const float*)d_in[16];
    const float* bti  = (const float*)d_in[17];
    const float* alphat = (const float*)d_in[18];
    const float* att0t  = (const float*)d_in[19];
    const float* Wto  = (const float*)d_in[20];
    const float* bto  = (const float*)d_in[21];
    const float* gto  = (const float*)d_in[22];
    const float* beto = (const float*)d_in[23];
    const float* Wtf  = (const float*)d_in[24];
    const float* btf  = (const float*)d_in[25];
    const float* gtf  = (const float*)d_in[26];
    const float* betf = (const float*)d_in[27];

    float* outp = (float*)d_out;
    const float* outpB = outp + 4ull * SAMP;   // samples 4..7 view

    int G = 1;
    for (int g = 8; g >= 1; g >>= 1) {
        if ((size_t)g * 27587500ull <= ws_size) { G = g; break; }
    }

    float* A   = (float*)d_ws;                       // qk / qkT, then h overlay
    float* Zs  = A  + (size_t)G * 3840000ull;        // z slice / score partials
    float* aT  = Zs + (size_t)G * 2560000ull;        // temporal att
    float* sp  = aT + (size_t)G * 480000ull;         // (unused, kept for layout)
    float* as  = sp + (size_t)G * 15000ull;          // spatial att

    dim3 blk(256);
    for (int n0 = 0; n0 < 8; n0 += G) {
        dim3 gIn(79, 3, G), gOut(79, 2, G);

        // ---- spatial stage (input x / x1) ----
        gemm_conv<0, true, true, false><<<gIn, blk, 0, stream>>>(
            Wsi, 256, bsi, nullptr, nullptr, x, x1, nullptr, pe_s,
            nullptr, nullptr, A, n0, 384, 256);
        scores_s_partial<<<dim3(200, 3, G), blk, 0, stream>>>(A, Zs);
        scores_s_final<<<dim3(3 * G), dim3(640), 0, stream>>>(Zs, alphas, att0s, as);
        for (int s = 0; s < 3; s++) {
            apply_s_kernel<<<dim3(200, G), blk, 0, stream>>>(x, x1, as, Zs, n0, s);
            if (s == 0)
                gemm_conv<2, false, false, false><<<gOut, blk, 0, stream>>>(
                    Wso + s * 256, 768, nullptr, nullptr, nullptr, nullptr, nullptr, Zs,
                    nullptr, nullptr, nullptr, A, n0, 256, 256);
            else if (s == 1)
                gemm_conv<3, false, false, false><<<gOut, blk, 0, stream>>>(
                    Wso + s * 256, 768, nullptr, nullptr, nullptr, nullptr, nullptr, Zs,
                    nullptr, nullptr, nullptr, A, n0, 256, 256);
            else
                gemm_conv<4, false, false, false><<<gOut, blk, 0, stream>>>(
                    Wso + s * 256, 768, bso, gso, beso, nullptr, nullptr, Zs,
                    nullptr, x, x1, A, n0, 256, 256);
        }
        gemm_conv<1, false, false, true><<<gOut, blk, 0, stream>>>(
            Wsf, 256, bsf, gsf, besf, nullptr, nullptr, A, nullptr,
            x, x1, outp, n0, 256, 256);

        // ---- temporal stage (input d_out, in place) ----
        gemm_conv<5, true, true, false><<<gIn, blk, 0, stream>>>(
            Wti, 256, bti, nullptr, nullptr, outp, outpB, nullptr, pe_t,
            nullptr, nullptr, A, n0, 384, 256);
        scores_t_gemm<<<dim3(49, 2, 3 * G), blk, 0, stream>>>(A, Zs);
        scores_t_final<<<dim3(625, 3 * G), blk, 0, stream>>>(Zs, alphat, att0t, aT);
        for (int s = 0; s < 3; s++) {
            apply_t_kernel<<<dim3(50, 4, G), blk, 0, stream>>>(outp, aT, Zs, n0, s);
            if (s == 0)
                gemm_conv<2, false, false, false><<<gOut, blk, 0, stream>>>(
                    Wto + s * 256, 768, nullptr, nullptr, nullptr, nullptr, nullptr, Zs,
                    nullptr, nullptr, nullptr, A, n0, 256, 256);
            else if (s == 1)
                gemm_conv<3, false, false, false><<<gOut, blk, 0, stream>>>(
                    Wto + s * 256, 768, nullptr, nullptr, nullptr, nullptr, nullptr, Zs,
                    nullptr, nullptr, nullptr, A, n0, 256, 256);
            else
                gemm_conv<4, false, false, false><<<gOut, blk, 0, stream>>>(
                    Wto + s * 256, 768, bto, gto, beto, nullptr, nullptr, Zs,
                    nullptr, outp, outpB, A, n0, 256, 256);
        }
        gemm_conv<1, false, false, true><<<gOut, blk, 0, stream>>>(
            Wtf, 256, btf, gtf, betf, nullptr, nullptr, A, nullptr,
            outp, outpB, outp, n0, 256, 256);
    }
}